// Round 3
// baseline (218.904 us; speedup 1.0000x reference)
//
#include <hip/hip_runtime.h>

#define H 64
#define NPIX 65536
#define LBATCH 8
#define LC 24
#define EPSF 1e-6f
#define LN2_50 34.6573590f // 50 * ln(2): U50 = 50*(ln a - ln b) = LN2_50*(log2 a - log2 b)

typedef _Float16 h8 __attribute__((ext_vector_type(8)));   // MFMA operand view
typedef __fp16   g2 __attribute__((ext_vector_type(2)));   // cvt_pkrtz result view
typedef float f32x16 __attribute__((ext_vector_type(16)));
union H8u { h8 v8; g2 v2[4]; };                            // layout-identical pun

// inverse-quadratic RBF eval on pre-scaled coords: 1/(1+d^2)
#define KEV(d) __builtin_amdgcn_rcpf(fmaf((d), (d), 1.0f))
#define PK(a, b) __builtin_amdgcn_cvt_pkrtz((a), (b))

// One block per (lc, PBT-pixel chunk). Staging (U/V/W) and the 64x64 merge
// histogram ALIAS the same LDS buffer (staging is dead once the K-loop ends),
// so LDS = max(3*PBT, 4096) floats. K-loop uses explicit 1-deep prefetch of
// the next step's 6 float4 broadcast reads so ds_read latency hides under the
// ~350-cycle eval of the current step. No global atomics anywhere.
template <int PBT>
__global__ __launch_bounds__(256, 3) void hist_main(const float* __restrict__ x,
                                                    float* __restrict__ ws) {
    constexpr int SB = (3 * PBT > H * H) ? 3 * PBT : H * H;
    __shared__ float sBuf[SB];
    float* const sU = sBuf;
    float* const sV = sBuf + PBT;
    float* const sW = sBuf + 2 * PBT;

    const int tid  = threadIdx.x;
    const int wv   = tid >> 6;
    const int lane = tid & 63;
    const int hf   = lane >> 5;
    const int ln   = lane & 31;
    const int lc   = blockIdx.y;
    const int l    = lc / 3;
    const int c    = lc - 3 * l;

    const float* __restrict__ x0p = x + (l * 3 + 0) * NPIX;
    const float* __restrict__ x1p = x + (l * 3 + 1) * NPIX;
    const float* __restrict__ x2p = x + (l * 3 + 2) * NPIX;
    const int base = blockIdx.x * PBT;

    // ---- Phase 1: cooperative pixel prep (4 px/thread/pass) ----
    #pragma unroll
    for (int pass = 0; pass < PBT / 1024; pass++) {
        const int ploc = pass * 1024 + tid * 4;
        const float4 r0 = *(const float4*)&x0p[base + ploc];
        const float4 r1 = *(const float4*)&x1p[base + ploc];
        const float4 r2 = *(const float4*)&x2p[base + ploc];
        float4 U4, V4, W4;
        #define PREP(E) { \
            const float v0 = fminf(fmaxf(r0.E, 0.0f), 1.0f); \
            const float v1 = fminf(fmaxf(r1.E, 0.0f), 1.0f); \
            const float v2 = fminf(fmaxf(r2.E, 0.0f), 1.0f); \
            W4.E = __builtin_amdgcn_sqrtf(fmaf(v0, v0, fmaf(v1, v1, fmaf(v2, v2, EPSF)))); \
            const float lg0 = __builtin_amdgcn_logf(v0 + EPSF); \
            const float lg1 = __builtin_amdgcn_logf(v1 + EPSF); \
            const float lg2 = __builtin_amdgcn_logf(v2 + EPSF); \
            float U, V; \
            if (c == 0)      { U = lg0 - lg1; V = lg0 - lg2; } \
            else if (c == 1) { U = lg1 - lg0; V = lg1 - lg2; } \
            else             { U = lg2 - lg0; V = lg2 - lg1; } \
            U4.E = LN2_50 * U; V4.E = LN2_50 * V; }
        PREP(x) PREP(y) PREP(z) PREP(w)
        #undef PREP
        *(float4*)&sU[ploc] = U4;
        *(float4*)&sV[ploc] = V4;
        *(float4*)&sW[ploc] = W4;
    }
    __syncthreads();

    // ---- Phase 2: MFMA K-loop over this wave's PBT/4-pixel slice ----
    const float step50 = 50.0f * (6.0f / 63.0f);
    const float ou0 = -150.0f + step50 * (float)ln;  // u/v bins [0,32)
    const float ou1 = ou0 + step50 * 32.0f;          // u/v bins [32,64)

    f32x16 acc00, acc01, acc10, acc11;
    #pragma unroll
    for (int i = 0; i < 16; i++) { acc00[i] = 0.f; acc01[i] = 0.f; acc10[i] = 0.f; acc11[i] = 0.f; }

    const int wbase = wv * (PBT / 4);
    constexpr int KSTEPS = PBT / 64;

    float4 cua, cub, cva, cvb, cwa, cwb;   // current K-step operands
    float4 pua, pub, pva, pvb, pwa, pwb;   // prefetched next K-step operands

    #define LOADK(P, ks) { const int kb = wbase + (ks) * 16 + hf * 8; \
        P##ua = *(const float4*)&sU[kb]; P##ub = *(const float4*)&sU[kb + 4]; \
        P##va = *(const float4*)&sV[kb]; P##vb = *(const float4*)&sV[kb + 4]; \
        P##wa = *(const float4*)&sW[kb]; P##wb = *(const float4*)&sW[kb + 4]; }

    #define BODY() { H8u A0, A1, B0, B1; \
        A0.v2[0] = PK(cwa.x * KEV(cua.x - ou0), cwa.y * KEV(cua.y - ou0)); \
        A0.v2[1] = PK(cwa.z * KEV(cua.z - ou0), cwa.w * KEV(cua.w - ou0)); \
        A0.v2[2] = PK(cwb.x * KEV(cub.x - ou0), cwb.y * KEV(cub.y - ou0)); \
        A0.v2[3] = PK(cwb.z * KEV(cub.z - ou0), cwb.w * KEV(cub.w - ou0)); \
        B0.v2[0] = PK(KEV(cva.x - ou0), KEV(cva.y - ou0)); \
        B0.v2[1] = PK(KEV(cva.z - ou0), KEV(cva.w - ou0)); \
        B0.v2[2] = PK(KEV(cvb.x - ou0), KEV(cvb.y - ou0)); \
        B0.v2[3] = PK(KEV(cvb.z - ou0), KEV(cvb.w - ou0)); \
        acc00 = __builtin_amdgcn_mfma_f32_32x32x16_f16(A0.v8, B0.v8, acc00, 0, 0, 0); \
        A1.v2[0] = PK(cwa.x * KEV(cua.x - ou1), cwa.y * KEV(cua.y - ou1)); \
        A1.v2[1] = PK(cwa.z * KEV(cua.z - ou1), cwa.w * KEV(cua.w - ou1)); \
        A1.v2[2] = PK(cwb.x * KEV(cub.x - ou1), cwb.y * KEV(cub.y - ou1)); \
        A1.v2[3] = PK(cwb.z * KEV(cub.z - ou1), cwb.w * KEV(cub.w - ou1)); \
        acc10 = __builtin_amdgcn_mfma_f32_32x32x16_f16(A1.v8, B0.v8, acc10, 0, 0, 0); \
        B1.v2[0] = PK(KEV(cva.x - ou1), KEV(cva.y - ou1)); \
        B1.v2[1] = PK(KEV(cva.z - ou1), KEV(cva.w - ou1)); \
        B1.v2[2] = PK(KEV(cvb.x - ou1), KEV(cvb.y - ou1)); \
        B1.v2[3] = PK(KEV(cvb.z - ou1), KEV(cvb.w - ou1)); \
        acc01 = __builtin_amdgcn_mfma_f32_32x32x16_f16(A0.v8, B1.v8, acc01, 0, 0, 0); \
        acc11 = __builtin_amdgcn_mfma_f32_32x32x16_f16(A1.v8, B1.v8, acc11, 0, 0, 0); }

    LOADK(c, 0)
    #pragma unroll 2
    for (int ks = 0; ks < KSTEPS - 1; ks++) {
        LOADK(p, ks + 1)           // issue next-step broadcast reads early
        BODY()                     // ~350 cycles of eval hides the latency
        cua = pua; cub = pub; cva = pva; cvb = pvb; cwa = pwa; cwb = pwb;
    }
    BODY()                         // peeled last step (no prefetch)
    #undef LOADK
    #undef BODY

    __syncthreads();               // staging now dead -> reuse LDS as histogram

    #pragma unroll
    for (int r = 0; r < H * H / 1024; r++)
        *(float4*)&sBuf[(r * 256 + tid) * 4] = make_float4(0.f, 0.f, 0.f, 0.f);
    __syncthreads();

    // merge 4 wave accumulators (C/D layout: col=ln, row=(r&3)+8*(r>>2)+4*hf)
    #pragma unroll
    for (int r = 0; r < 16; r++) {
        const int row = (r & 3) + 8 * (r >> 2) + 4 * hf;
        atomicAdd(&sBuf[row * 64 + ln],             acc00[r]);
        atomicAdd(&sBuf[row * 64 + 32 + ln],        acc01[r]);
        atomicAdd(&sBuf[(row + 32) * 64 + ln],      acc10[r]);
        atomicAdd(&sBuf[(row + 32) * 64 + 32 + ln], acc11[r]);
    }
    __syncthreads();

    // flush partial histogram to private ws slice — plain streaming stores
    float* __restrict__ g = ws + (blockIdx.y * gridDim.x + blockIdx.x) * (H * H);
    #pragma unroll
    for (int r = 0; r < 4; r++) {
        const int i = (r * 256 + tid) * 4;
        *(float4*)&g[i] = *(const float4*)&sBuf[i];
    }
}

// 96 blocks: one per (lc, quarter). Sum nch chunk-partials, write out,
// emit per-block mass partial to wsq (plain store — no atomics, no zeroing).
__global__ __launch_bounds__(256) void hist_reduce(const float* __restrict__ ws,
                                                   float* __restrict__ out,
                                                   float* __restrict__ wsq,
                                                   int nch) {
    const int lc  = blockIdx.x >> 2;
    const int off = (blockIdx.x & 3) * 1024 + threadIdx.x * 4;
    float4 a = make_float4(0.f, 0.f, 0.f, 0.f);
    #pragma unroll 8
    for (int ch = 0; ch < nch; ch++) {
        const float4 v = *(const float4*)&ws[(lc * nch + ch) * (H * H) + off];
        a.x += v.x; a.y += v.y; a.z += v.z; a.w += v.w;
    }
    *(float4*)&out[lc * (H * H) + off] = a;

    float s = (a.x + a.y) + (a.z + a.w);
    #pragma unroll
    for (int o = 32; o > 0; o >>= 1) s += __shfl_down(s, o, 64);
    __shared__ float ps[4];
    if ((threadIdx.x & 63) == 0) ps[threadIdx.x >> 6] = s;
    __syncthreads();
    if (threadIdx.x == 0) wsq[blockIdx.x] = (ps[0] + ps[1]) + (ps[2] + ps[3]);
}

// 96 blocks: normalize. Total for sample l = sum of its 12 wsq partials.
__global__ __launch_bounds__(256) void hist_scale(float* __restrict__ out,
                                                  const float* __restrict__ wsq) {
    const int lc = blockIdx.x >> 2;
    const int l  = lc / 3;
    float T = 0.f;
    #pragma unroll
    for (int j = 0; j < 12; j++) T += wsq[l * 12 + j];
    const float inv = 1.0f / (T + EPSF);
    const int off = (blockIdx.x & 3) * 1024 + threadIdx.x * 4;
    float4 v = *(const float4*)&out[lc * (H * H) + off];
    v.x *= inv; v.y *= inv; v.z *= inv; v.w *= inv;
    *(float4*)&out[lc * (H * H) + off] = v;
}

extern "C" void kernel_launch(void* const* d_in, const int* in_sizes, int n_in,
                              void* d_out, int out_size, void* d_ws, size_t ws_size,
                              hipStream_t stream) {
    const float* x = (const float*)d_in[0];
    float* out = (float*)d_out;
    float* ws = (float*)d_ws;

    // Primary: 64 chunks x 24 lc = 1536 blocks (needs 25.2 MB workspace).
    // Fallback: proven 32-chunk geometry (12.6 MB), if d_ws is small.
    const size_t need64 = ((size_t)64 * LC * H * H + 96) * sizeof(float);
    if (ws_size >= need64) {
        float* wsq = ws + (size_t)64 * LC * H * H;
        hipLaunchKernelGGL(hist_main<1024>, dim3(64, LC), dim3(256), 0, stream, x, ws);
        hipLaunchKernelGGL(hist_reduce,     dim3(96),     dim3(256), 0, stream, ws, out, wsq, 64);
        hipLaunchKernelGGL(hist_scale,      dim3(96),     dim3(256), 0, stream, out, wsq);
    } else {
        float* wsq = ws + (size_t)32 * LC * H * H;
        hipLaunchKernelGGL(hist_main<2048>, dim3(32, LC), dim3(256), 0, stream, x, ws);
        hipLaunchKernelGGL(hist_reduce,     dim3(96),     dim3(256), 0, stream, ws, out, wsq, 32);
        hipLaunchKernelGGL(hist_scale,      dim3(96),     dim3(256), 0, stream, out, wsq);
    }
}

// Round 4
// 157.068 us; speedup vs baseline: 1.3937x; 1.3937x over previous
//
#include <hip/hip_runtime.h>

#define H 64
#define NPIX 65536
#define LBATCH 8
#define LC 24
#define S_CHUNKS 32
#define PB 2048            // pixels per block
#define EPSF 1e-6f
#define LN2_50 34.6573590f // 50 * ln(2): U50 = 50*(ln a - ln b) = LN2_50*(log2 a - log2 b)
#define NPART (LC * S_CHUNKS)        // 768 partial histograms
#define PART_FLOATS (NPART * H * H)  // 12.58 MB of d_ws

typedef _Float16 h8 __attribute__((ext_vector_type(8)));   // MFMA operand view
typedef __fp16   g2 __attribute__((ext_vector_type(2)));   // cvt_pkrtz result view
typedef float f32x16 __attribute__((ext_vector_type(16)));
union H8u { h8 v8; g2 v2[4]; };                            // layout-identical pun

#define PK(a, b) __builtin_amdgcn_cvt_pkrtz((a), (b))

// 4 inverse-quadratic evals with ONE v_rcp_f32 (TRANS pipe is the bottleneck):
// 1/q_i = (prod of other three q) * rcp(q0*q1*q2*q3). q in [1, 7e5] so the
// product <= 2.4e23 stays normal-range fp32; extra rounding ~3e-7 relative.
#define KEV4(k0, k1, k2, k3, d0, d1, d2, d3) { \
    const float q0 = fmaf((d0), (d0), 1.0f); \
    const float q1 = fmaf((d1), (d1), 1.0f); \
    const float q2 = fmaf((d2), (d2), 1.0f); \
    const float q3 = fmaf((d3), (d3), 1.0f); \
    const float p01 = q0 * q1, p23 = q2 * q3; \
    const float r = __builtin_amdgcn_rcpf(p01 * p23); \
    const float r23 = p23 * r, r01 = p01 * r; \
    k0 = q1 * r23; k1 = q0 * r23; k2 = q3 * r01; k3 = q2 * r01; }

// One block per (lc, 2048-pixel chunk) — geometry identical to the proven
// 102us config; ONLY the RBF eval math changed (4x fewer rcp).
__global__ __launch_bounds__(256, 3) void hist_main(const float* __restrict__ x,
                                                    float* __restrict__ ws) {
    __shared__ float sU[PB];
    __shared__ float sV[PB];
    __shared__ float sW[PB];
    __shared__ float sHist[H * H];

    const int tid  = threadIdx.x;
    const int wv   = tid >> 6;
    const int lane = tid & 63;
    const int hf   = lane >> 5;
    const int ln   = lane & 31;
    const int lc   = blockIdx.y;
    const int l    = lc / 3;
    const int c    = lc - 3 * l;

    #pragma unroll
    for (int r = 0; r < 4; r++)
        *(float4*)&sHist[(r * 256 + tid) * 4] = make_float4(0.f, 0.f, 0.f, 0.f);

    const float* __restrict__ x0p = x + (l * 3 + 0) * NPIX;
    const float* __restrict__ x1p = x + (l * 3 + 1) * NPIX;
    const float* __restrict__ x2p = x + (l * 3 + 2) * NPIX;
    const int base = blockIdx.x * PB;

    // ---- Phase 1: cooperative pixel prep (2 passes x 4 px/thread) ----
    #pragma unroll
    for (int pass = 0; pass < 2; pass++) {
        const int ploc = pass * 1024 + tid * 4;
        const float4 r0 = *(const float4*)&x0p[base + ploc];
        const float4 r1 = *(const float4*)&x1p[base + ploc];
        const float4 r2 = *(const float4*)&x2p[base + ploc];
        float4 U4, V4, W4;
        #define PREP(E) { \
            const float v0 = fminf(fmaxf(r0.E, 0.0f), 1.0f); \
            const float v1 = fminf(fmaxf(r1.E, 0.0f), 1.0f); \
            const float v2 = fminf(fmaxf(r2.E, 0.0f), 1.0f); \
            W4.E = __builtin_amdgcn_sqrtf(fmaf(v0, v0, fmaf(v1, v1, fmaf(v2, v2, EPSF)))); \
            const float lg0 = __builtin_amdgcn_logf(v0 + EPSF); \
            const float lg1 = __builtin_amdgcn_logf(v1 + EPSF); \
            const float lg2 = __builtin_amdgcn_logf(v2 + EPSF); \
            float U, V; \
            if (c == 0)      { U = lg0 - lg1; V = lg0 - lg2; } \
            else if (c == 1) { U = lg1 - lg0; V = lg1 - lg2; } \
            else             { U = lg2 - lg0; V = lg2 - lg1; } \
            U4.E = LN2_50 * U; V4.E = LN2_50 * V; }
        PREP(x) PREP(y) PREP(z) PREP(w)
        #undef PREP
        *(float4*)&sU[ploc] = U4;
        *(float4*)&sV[ploc] = V4;
        *(float4*)&sW[ploc] = W4;
    }
    __syncthreads();

    // ---- Phase 2: MFMA K-loop over this wave's 512-pixel slice ----
    const float step50 = 50.0f * (6.0f / 63.0f);
    const float ou0 = -150.0f + step50 * (float)ln;  // u/v bins [0,32)
    const float ou1 = ou0 + step50 * 32.0f;          // u/v bins [32,64)

    f32x16 acc00, acc01, acc10, acc11;
    #pragma unroll
    for (int i = 0; i < 16; i++) { acc00[i] = 0.f; acc01[i] = 0.f; acc10[i] = 0.f; acc11[i] = 0.f; }

    const int wbase = wv * 512;
    #pragma unroll 2
    for (int ks = 0; ks < 32; ks++) {
        const int kb = wbase + ks * 16 + hf * 8;     // half-wave's 8 k-pixels
        const float4 ua = *(const float4*)&sU[kb];
        const float4 ub = *(const float4*)&sU[kb + 4];
        const float4 va = *(const float4*)&sV[kb];
        const float4 vb = *(const float4*)&sV[kb + 4];
        const float4 wa = *(const float4*)&sW[kb];
        const float4 wb = *(const float4*)&sW[kb + 4];
        H8u A0, A1, B0, B1;
        float k0, k1, k2, k3;
        KEV4(k0, k1, k2, k3, ua.x - ou0, ua.y - ou0, ua.z - ou0, ua.w - ou0)
        A0.v2[0] = PK(wa.x * k0, wa.y * k1);
        A0.v2[1] = PK(wa.z * k2, wa.w * k3);
        KEV4(k0, k1, k2, k3, ub.x - ou0, ub.y - ou0, ub.z - ou0, ub.w - ou0)
        A0.v2[2] = PK(wb.x * k0, wb.y * k1);
        A0.v2[3] = PK(wb.z * k2, wb.w * k3);
        KEV4(k0, k1, k2, k3, ua.x - ou1, ua.y - ou1, ua.z - ou1, ua.w - ou1)
        A1.v2[0] = PK(wa.x * k0, wa.y * k1);
        A1.v2[1] = PK(wa.z * k2, wa.w * k3);
        KEV4(k0, k1, k2, k3, ub.x - ou1, ub.y - ou1, ub.z - ou1, ub.w - ou1)
        A1.v2[2] = PK(wb.x * k0, wb.y * k1);
        A1.v2[3] = PK(wb.z * k2, wb.w * k3);
        KEV4(k0, k1, k2, k3, va.x - ou0, va.y - ou0, va.z - ou0, va.w - ou0)
        B0.v2[0] = PK(k0, k1);
        B0.v2[1] = PK(k2, k3);
        KEV4(k0, k1, k2, k3, vb.x - ou0, vb.y - ou0, vb.z - ou0, vb.w - ou0)
        B0.v2[2] = PK(k0, k1);
        B0.v2[3] = PK(k2, k3);
        KEV4(k0, k1, k2, k3, va.x - ou1, va.y - ou1, va.z - ou1, va.w - ou1)
        B1.v2[0] = PK(k0, k1);
        B1.v2[1] = PK(k2, k3);
        KEV4(k0, k1, k2, k3, vb.x - ou1, vb.y - ou1, vb.z - ou1, vb.w - ou1)
        B1.v2[2] = PK(k0, k1);
        B1.v2[3] = PK(k2, k3);
        acc00 = __builtin_amdgcn_mfma_f32_32x32x16_f16(A0.v8, B0.v8, acc00, 0, 0, 0);
        acc01 = __builtin_amdgcn_mfma_f32_32x32x16_f16(A0.v8, B1.v8, acc01, 0, 0, 0);
        acc10 = __builtin_amdgcn_mfma_f32_32x32x16_f16(A1.v8, B0.v8, acc10, 0, 0, 0);
        acc11 = __builtin_amdgcn_mfma_f32_32x32x16_f16(A1.v8, B1.v8, acc11, 0, 0, 0);
    }

    // merge 4 wave accumulators (C/D layout: col=ln, row=(r&3)+8*(r>>2)+4*hf)
    #pragma unroll
    for (int r = 0; r < 16; r++) {
        const int row = (r & 3) + 8 * (r >> 2) + 4 * hf;
        atomicAdd(&sHist[row * 64 + ln],             acc00[r]);
        atomicAdd(&sHist[row * 64 + 32 + ln],        acc01[r]);
        atomicAdd(&sHist[(row + 32) * 64 + ln],      acc10[r]);
        atomicAdd(&sHist[(row + 32) * 64 + 32 + ln], acc11[r]);
    }
    __syncthreads();

    // flush partial histogram to private ws slice — plain streaming stores
    float* __restrict__ g = ws + (lc * S_CHUNKS + blockIdx.x) * (H * H);
    #pragma unroll
    for (int r = 0; r < 4; r++) {
        const int i = (r * 256 + tid) * 4;
        *(float4*)&g[i] = *(const float4*)&sHist[i];
    }
}

// 96 blocks: one per (lc, quarter). Sum 32 chunk-partials, write out,
// emit per-block mass partial to wsq (plain store — no atomics, no zeroing).
__global__ __launch_bounds__(256) void hist_reduce(const float* __restrict__ ws,
                                                   float* __restrict__ out,
                                                   float* __restrict__ wsq) {
    const int lc  = blockIdx.x >> 2;
    const int off = (blockIdx.x & 3) * 1024 + threadIdx.x * 4;
    float4 a = make_float4(0.f, 0.f, 0.f, 0.f);
    #pragma unroll 8
    for (int ch = 0; ch < S_CHUNKS; ch++) {
        const float4 v = *(const float4*)&ws[(lc * S_CHUNKS + ch) * (H * H) + off];
        a.x += v.x; a.y += v.y; a.z += v.z; a.w += v.w;
    }
    *(float4*)&out[lc * (H * H) + off] = a;

    float s = (a.x + a.y) + (a.z + a.w);
    #pragma unroll
    for (int o = 32; o > 0; o >>= 1) s += __shfl_down(s, o, 64);
    __shared__ float ps[4];
    if ((threadIdx.x & 63) == 0) ps[threadIdx.x >> 6] = s;
    __syncthreads();
    if (threadIdx.x == 0) wsq[blockIdx.x] = (ps[0] + ps[1]) + (ps[2] + ps[3]);
}

// 96 blocks: normalize. Total for sample l = sum of its 12 wsq partials.
__global__ __launch_bounds__(256) void hist_scale(float* __restrict__ out,
                                                  const float* __restrict__ wsq) {
    const int lc = blockIdx.x >> 2;
    const int l  = lc / 3;
    float T = 0.f;
    #pragma unroll
    for (int j = 0; j < 12; j++) T += wsq[l * 12 + j];
    const float inv = 1.0f / (T + EPSF);
    const int off = (blockIdx.x & 3) * 1024 + threadIdx.x * 4;
    float4 v = *(const float4*)&out[lc * (H * H) + off];
    v.x *= inv; v.y *= inv; v.z *= inv; v.w *= inv;
    *(float4*)&out[lc * (H * H) + off] = v;
}

extern "C" void kernel_launch(void* const* d_in, const int* in_sizes, int n_in,
                              void* d_out, int out_size, void* d_ws, size_t ws_size,
                              hipStream_t stream) {
    const float* x = (const float*)d_in[0];
    float* out = (float*)d_out;
    float* ws = (float*)d_ws;   // needs 12.58 MB + 384 B

    hipLaunchKernelGGL(hist_main,   dim3(S_CHUNKS, LC), dim3(256), 0, stream, x, ws);
    hipLaunchKernelGGL(hist_reduce, dim3(96),           dim3(256), 0, stream, ws, out, ws + PART_FLOATS);
    hipLaunchKernelGGL(hist_scale,  dim3(96),           dim3(256), 0, stream, out, ws + PART_FLOATS);
}